// Round 2
// baseline (262.938 us; speedup 1.0000x reference)
//
#include <hip/hip_runtime.h>
#include <math.h>

// MEASUREMENT ROUND: identical kernel launched TWICE back-to-back.
// The kernel is idempotent (reads x, writes out; out is not an input), so
// correctness is unchanged. dur_us_new - dur_us_prev isolates the kernel's
// own duration, which the top-5 rocprof cutoff hides behind the ~79us
// harness poison fills. This decides "kernel at copy ceiling (~43us)" vs
// "kernel at ~62us with ~19us headroom".

typedef float vfloat4 __attribute__((ext_vector_type(4)));

#define CHUNKS 8

__global__ __launch_bounds__(256) void rope2d_kernel(
    const vfloat4* __restrict__ x,
    const int* __restrict__ grid_sizes,
    vfloat4* __restrict__ out)
{
    const int tid   = threadIdx.x;
    const int base4 = blockIdx.x * (256 * CHUNKS);   // first float4 index of this block
    const int bs0   = blockIdx.x * CHUNKS;           // first (b*S+s) slice index

    // pair index within D: e_in_slice = tid*4 -> k = ((tid*4) & 63) >> 1 = (tid & 15)*2
    const int k = (tid & 15) << 1;

    const float C       = -0.41524101186092029f;  // -log2(10000)/32
    const float INV_2PI = 0.15915494309189535f;

    // theta / (2*pi), so the per-chunk angle is a single mul + fract.
    const float t0 = __builtin_amdgcn_exp2f((float)k * C) * INV_2PI;
    const float t1 = __builtin_amdgcn_exp2f((float)(k + 1) * C) * INV_2PI;

    // Issue all 8 loads before any compute (8 outstanding vmem ops per wave).
    vfloat4 v[CHUNKS];
#pragma unroll
    for (int c = 0; c < CHUNKS; ++c)
        v[c] = __builtin_nontemporal_load(&x[base4 + c * 256 + tid]);

    // One uniform division per block; all chunks share b since 1024 % CHUNKS == 0.
    const int s0   = bs0 & 1023;               // S = 1024
    const int b    = bs0 >> 10;
    const int cols = grid_sizes[2 * b + 1];    // uniform scalar load
    int i = s0 / cols;                         // uniform division, once per block
    int j = s0 - i * cols;

#pragma unroll
    for (int c = 0; c < CHUNKS; ++c) {
        const float ij = (float)(i + j);

        float r0 = ij * t0;  r0 -= floorf(r0);
        float r1 = ij * t1;  r1 -= floorf(r1);

        const float sn0 = __builtin_amdgcn_sinf(r0);
        const float cs0 = __builtin_amdgcn_cosf(r0);
        const float sn1 = __builtin_amdgcn_sinf(r1);
        const float cs1 = __builtin_amdgcn_cosf(r1);

        vfloat4 o;
        o.x = v[c].x * cs0 - v[c].y * sn0;
        o.y = v[c].y * cs0 + v[c].x * sn0;
        o.z = v[c].z * cs1 - v[c].w * sn1;
        o.w = v[c].w * cs1 + v[c].z * sn1;
        __builtin_nontemporal_store(o, &out[base4 + c * 256 + tid]);

        // advance (i, j) to the next s (increment + wrap; no per-chunk division)
        ++j;
        if (j == cols) { j = 0; ++i; }
    }
}

extern "C" void kernel_launch(void* const* d_in, const int* in_sizes, int n_in,
                              void* d_out, int out_size, void* d_ws, size_t ws_size,
                              hipStream_t stream) {
    const vfloat4* x  = (const vfloat4*)d_in[0];
    const int*     gs = (const int*)d_in[1];
    vfloat4*       o  = (vfloat4*)d_out;

    const int n4     = in_sizes[0] >> 2;            // 8,388,608 float4s
    const int blocks = n4 / (256 * CHUNKS);         // 4096 blocks, exact coverage

    // Launch TWICE: second launch recomputes the identical output from x.
    // dur_us delta vs. previous round == one kernel duration.
    rope2d_kernel<<<blocks, 256, 0, stream>>>(x, gs, o);
    rope2d_kernel<<<blocks, 256, 0, stream>>>(x, gs, o);
}

// Round 3
// 217.738 us; speedup vs baseline: 1.2076x; 1.2076x over previous
//
#include <hip/hip_runtime.h>
#include <math.h>

// RoPE-2D fused: R(col)*R(row) = R(row+col) (2D rotations compose additively).
// x: [B=32, S=1024, H=16, D=64] fp32. One (b,s) slice = H*D = 1024 floats = 256 float4s.
// Block = 256 threads, handles 8 consecutive (b,s) slices (128 B/thread).
// 1024 % 8 == 0 -> all 8 chunks of a block share the same b (one cols load,
// ONE uniform integer division per block; (i,j) advanced by increment+wrap).
// All 8 nontemporal loads issued before any compute for HBM latency hiding.
//
// ROOFLINE EVIDENCE (Round-2 double-launch measurement): one kernel launch
// = 43.2 us for 268.4 MB of traffic = 6.21 TB/s = 98.7% of the measured
// float4-copy ceiling (6.29 TB/s) on MI355X. The remaining ~176 us of the
// timed region is harness poison fills (~79 us each at 85% HBM peak).
// Memory-bound limit reached; compute is ~5% VALUBusy.

typedef float vfloat4 __attribute__((ext_vector_type(4)));

#define CHUNKS 8

__global__ __launch_bounds__(256) void rope2d_kernel(
    const vfloat4* __restrict__ x,
    const int* __restrict__ grid_sizes,
    vfloat4* __restrict__ out)
{
    const int tid   = threadIdx.x;
    const int base4 = blockIdx.x * (256 * CHUNKS);   // first float4 index of this block
    const int bs0   = blockIdx.x * CHUNKS;           // first (b*S+s) slice index

    // pair index within D: e_in_slice = tid*4 -> k = ((tid*4) & 63) >> 1 = (tid & 15)*2
    const int k = (tid & 15) << 1;

    const float C       = -0.41524101186092029f;  // -log2(10000)/32
    const float INV_2PI = 0.15915494309189535f;

    // theta / (2*pi), so the per-chunk angle is a single mul + fract.
    const float t0 = __builtin_amdgcn_exp2f((float)k * C) * INV_2PI;
    const float t1 = __builtin_amdgcn_exp2f((float)(k + 1) * C) * INV_2PI;

    // Issue all 8 loads before any compute (8 outstanding vmem ops per wave).
    vfloat4 v[CHUNKS];
#pragma unroll
    for (int c = 0; c < CHUNKS; ++c)
        v[c] = __builtin_nontemporal_load(&x[base4 + c * 256 + tid]);

    // One uniform division per block; all chunks share b since 1024 % CHUNKS == 0.
    const int s0   = bs0 & 1023;               // S = 1024
    const int b    = bs0 >> 10;
    const int cols = grid_sizes[2 * b + 1];    // uniform scalar load
    int i = s0 / cols;                         // uniform division, once per block
    int j = s0 - i * cols;

#pragma unroll
    for (int c = 0; c < CHUNKS; ++c) {
        const float ij = (float)(i + j);

        float r0 = ij * t0;  r0 -= floorf(r0);
        float r1 = ij * t1;  r1 -= floorf(r1);

        const float sn0 = __builtin_amdgcn_sinf(r0);
        const float cs0 = __builtin_amdgcn_cosf(r0);
        const float sn1 = __builtin_amdgcn_sinf(r1);
        const float cs1 = __builtin_amdgcn_cosf(r1);

        vfloat4 o;
        o.x = v[c].x * cs0 - v[c].y * sn0;
        o.y = v[c].y * cs0 + v[c].x * sn0;
        o.z = v[c].z * cs1 - v[c].w * sn1;
        o.w = v[c].w * cs1 + v[c].z * sn1;
        __builtin_nontemporal_store(o, &out[base4 + c * 256 + tid]);

        // advance (i, j) to the next s (increment + wrap; no per-chunk division)
        ++j;
        if (j == cols) { j = 0; ++i; }
    }
}

extern "C" void kernel_launch(void* const* d_in, const int* in_sizes, int n_in,
                              void* d_out, int out_size, void* d_ws, size_t ws_size,
                              hipStream_t stream) {
    const vfloat4* x  = (const vfloat4*)d_in[0];
    const int*     gs = (const int*)d_in[1];
    vfloat4*       o  = (vfloat4*)d_out;

    const int n4     = in_sizes[0] >> 2;            // 8,388,608 float4s
    const int blocks = n4 / (256 * CHUNKS);         // 4096 blocks, exact coverage

    rope2d_kernel<<<blocks, 256, 0, stream>>>(x, gs, o);
}